// Round 1
// baseline (110.511 us; speedup 1.0000x reference)
//
#include <hip/hip_runtime.h>

// BuildCombinationsDim2: out[b,t,j] = x[b,t, idx[j]] where idx is the
// flattened list of k=2 combinations of F=32 features (lexicographic):
// idx = [0,1, 0,2, ..., 0,31, 1,2, ..., 30,31], ncr = 2*C(32,2) = 992.
// Pure gather along the last axis; write-bandwidth-bound (520 MB out, 16 MB in).

#define FDIM 32
#define NCR 992            // k * C(F,2)
#define G_PER_ROW 248      // NCR / 4 float4 groups per row
#define ROWS_PER_BLOCK 8
#define BLOCK 256

__global__ __launch_bounds__(BLOCK)
void comb_gather_kernel(const float* __restrict__ x,
                        float* __restrict__ out,
                        int nrows) {
    __shared__ float lds[ROWS_PER_BLOCK * FDIM];   // 8 rows * 32 f32 = 1 KB

    const int tid  = threadIdx.x;
    const int row0 = blockIdx.x * ROWS_PER_BLOCK;

    // Stage up to 8 input rows (256 floats = 64 float4) into LDS, coalesced.
    if (tid < (ROWS_PER_BLOCK * FDIM) / 4) {
        // Guard against a partial last block (not hit at 131072 rows, but cheap).
        int row_of_load = row0 + (tid * 4) / FDIM;
        if (row_of_load < nrows) {
            const float4* src = reinterpret_cast<const float4*>(x + (size_t)row0 * FDIM);
            reinterpret_cast<float4*>(lds)[tid] = src[tid];
        }
    }

    // Each thread owns float4 group g covering output columns j = 4g..4g+3.
    // Compute the 4 gather feature ids once: column j -> pair c = j>>1,
    // position pos = j&1. Invert the lexicographic cumsum to get (i, second).
    int feat[4];
    const int g = tid;
    if (g < G_PER_ROW) {
        #pragma unroll
        for (int u = 0; u < 4; ++u) {
            int j   = g * 4 + u;
            int c   = j >> 1;
            int pos = j & 1;
            int i = 0, cum = 0;
            while (cum + (FDIM - 1 - i) <= c) { cum += FDIM - 1 - i; ++i; }
            int second = c - cum + i + 1;
            feat[u] = pos ? second : i;
        }
    }
    __syncthreads();

    if (g >= G_PER_ROW) return;

    #pragma unroll
    for (int r = 0; r < ROWS_PER_BLOCK; ++r) {
        int row = row0 + r;
        if (row >= nrows) break;
        const float* rowp = lds + r * FDIM;   // all lanes same row -> LDS broadcast
        float4 v;
        v.x = rowp[feat[0]];
        v.y = rowp[feat[1]];
        v.z = rowp[feat[2]];
        v.w = rowp[feat[3]];
        reinterpret_cast<float4*>(out + (size_t)row * NCR)[g] = v;
    }
}

extern "C" void kernel_launch(void* const* d_in, const int* in_sizes, int n_in,
                              void* d_out, int out_size, void* d_ws, size_t ws_size,
                              hipStream_t stream) {
    const float* x  = (const float*)d_in[0];
    float* out      = (float*)d_out;
    // in_sizes[0] = B*T*F; F = 32 per the reference setup (k=2 likewise fixed).
    int nrows = in_sizes[0] / FDIM;                       // 32*4096 = 131072
    int grid  = (nrows + ROWS_PER_BLOCK - 1) / ROWS_PER_BLOCK;  // 16384
    hipLaunchKernelGGL(comb_gather_kernel, dim3(grid), dim3(BLOCK), 0, stream,
                       x, out, nrows);
}

// Round 3
// 104.357 us; speedup vs baseline: 1.0590x; 1.0590x over previous
//
#include <hip/hip_runtime.h>

// BuildCombinationsDim2: out[b,t,j] = x[b,t, idx[j]] where idx is the
// flattened list of k=2 combinations of F=32 features (lexicographic).
// ncr = 2*C(32,2) = 992. Pure gather along last axis; write-BW-bound.
// R2: non-temporal stores via native clang vector type (HIP float4 is a
// class and rejected by __builtin_nontemporal_store).

#define FDIM 32
#define NCR 992            // k * C(F,2)
#define G_PER_ROW 248      // NCR / 4 float4 groups per row
#define ROWS_PER_BLOCK 8
#define BLOCK 256

typedef float f32x4 __attribute__((ext_vector_type(4)));

__global__ __launch_bounds__(BLOCK)
void comb_gather_kernel(const float* __restrict__ x,
                        float* __restrict__ out,
                        int nrows) {
    __shared__ float lds[ROWS_PER_BLOCK * FDIM];   // 8 rows * 32 f32 = 1 KB

    const int tid  = threadIdx.x;
    const int row0 = blockIdx.x * ROWS_PER_BLOCK;
    const bool full = (row0 + ROWS_PER_BLOCK) <= nrows;

    // Stage 8 input rows (256 floats = 64 float4) into LDS, coalesced.
    if (tid < (ROWS_PER_BLOCK * FDIM) / 4) {
        const f32x4* src = reinterpret_cast<const f32x4*>(x + (size_t)row0 * FDIM);
        if (full) {
            reinterpret_cast<f32x4*>(lds)[tid] = src[tid];
        } else {
            int row_of_load = row0 + (tid * 4) / FDIM;
            if (row_of_load < nrows)
                reinterpret_cast<f32x4*>(lds)[tid] = src[tid];
        }
    }

    // Each thread owns float4 group g covering output columns j = 4g..4g+3.
    // Column j -> combination c = j>>1, position pos = j&1. Invert the
    // lexicographic cumsum once to get the two member feature ids.
    int feat[4];
    const int g = tid;
    if (g < G_PER_ROW) {
        #pragma unroll
        for (int u = 0; u < 4; ++u) {
            int j   = g * 4 + u;
            int c   = j >> 1;
            int pos = j & 1;
            int i = 0, cum = 0;
            while (cum + (FDIM - 1 - i) <= c) { cum += FDIM - 1 - i; ++i; }
            int second = c - cum + i + 1;
            feat[u] = pos ? second : i;
        }
    }
    __syncthreads();

    if (g >= G_PER_ROW) return;

    if (full) {
        // Branch-free: 8 independent LDS-gather + nt-store iterations.
        f32x4* outp = reinterpret_cast<f32x4*>(out + (size_t)row0 * NCR) + g;
        #pragma unroll
        for (int r = 0; r < ROWS_PER_BLOCK; ++r) {
            const float* rowp = lds + r * FDIM;   // same row across lanes -> broadcast
            f32x4 v;
            v.x = rowp[feat[0]];
            v.y = rowp[feat[1]];
            v.z = rowp[feat[2]];
            v.w = rowp[feat[3]];
            // Streaming output, never re-read: bypass L2 write-allocate.
            __builtin_nontemporal_store(v, outp);
            outp += NCR / 4;
        }
    } else {
        #pragma unroll
        for (int r = 0; r < ROWS_PER_BLOCK; ++r) {
            int row = row0 + r;
            if (row >= nrows) break;
            const float* rowp = lds + r * FDIM;
            f32x4 v;
            v.x = rowp[feat[0]];
            v.y = rowp[feat[1]];
            v.z = rowp[feat[2]];
            v.w = rowp[feat[3]];
            __builtin_nontemporal_store(
                v, reinterpret_cast<f32x4*>(out + (size_t)row * NCR) + g);
        }
    }
}

extern "C" void kernel_launch(void* const* d_in, const int* in_sizes, int n_in,
                              void* d_out, int out_size, void* d_ws, size_t ws_size,
                              hipStream_t stream) {
    const float* x  = (const float*)d_in[0];
    float* out      = (float*)d_out;
    int nrows = in_sizes[0] / FDIM;                       // 32*4096 = 131072
    int grid  = (nrows + ROWS_PER_BLOCK - 1) / ROWS_PER_BLOCK;  // 16384
    hipLaunchKernelGGL(comb_gather_kernel, dim3(grid), dim3(BLOCK), 0, stream,
                       x, out, nrows);
}

// Round 4
// 101.436 us; speedup vs baseline: 1.0895x; 1.0288x over previous
//
#include <hip/hip_runtime.h>

// BuildCombinationsDim2: out[b,t,j] = x[b,t, idx[j]] where idx is the
// flattened list of k=2 combinations of F=32 features (lexicographic).
// ncr = 2*C(32,2) = 992. Pure gather along last axis; write-BW-bound.
// R4: closed-form combination inversion (1 sqrt + fixup) replaces the
// ~700-instr divergent while loop; 16 rows/block; nt stores kept.

#define FDIM 32
#define NCR 992            // k * C(F,2)
#define G_PER_ROW 248      // NCR / 4 float4 groups per row
#define ROWS_PER_BLOCK 16
#define BLOCK 256

typedef float f32x4 __attribute__((ext_vector_type(4)));
typedef float f32x2 __attribute__((ext_vector_type(2)));

__global__ __launch_bounds__(BLOCK)
void comb_gather_kernel(const float* __restrict__ x,
                        float* __restrict__ out,
                        int nrows) {
    __shared__ float lds[ROWS_PER_BLOCK * FDIM];   // 16 rows * 32 f32 = 2 KB

    const int tid  = threadIdx.x;
    const int row0 = blockIdx.x * ROWS_PER_BLOCK;
    const bool full = (row0 + ROWS_PER_BLOCK) <= nrows;

    // Stage 16 input rows (512 floats = 256 float2) into LDS, coalesced:
    // every thread loads one float2.
    {
        const f32x2* src = reinterpret_cast<const f32x2*>(x + (size_t)row0 * FDIM);
        if (full) {
            reinterpret_cast<f32x2*>(lds)[tid] = src[tid];
        } else {
            int row_of_load = row0 + (tid * 2) / FDIM;
            if (row_of_load < nrows)
                reinterpret_cast<f32x2*>(lds)[tid] = src[tid];
        }
    }

    // Thread g owns output float4 group g: columns j = 4g..4g+3.
    // j -> combination c = j>>1 = 2g + (u>>1), position = j&1.
    // So only combinations c0 = 2g and c1 = 2g+1 are needed.
    // Invert lexicographic pair index in closed form:
    //   start(i) = i*(63-i)/2; first = max i with start(i) <= c;
    //   i = floor((63 - sqrt(3969 - 8c)) / 2), +-1 integer fixup.
    int feat[4];
    const int g = tid;
    if (g < G_PER_ROW) {
        const int c0 = 2 * g;
        float s = sqrtf(3969.0f - 8.0f * (float)c0);
        int i0 = (int)((63.0f - s) * 0.5f);
        if (i0 < 0) i0 = 0;
        int st0  = (i0 * (63 - i0)) >> 1;
        int stn0 = ((i0 + 1) * (62 - i0)) >> 1;
        if (stn0 <= c0) { i0++; st0 = stn0; stn0 = ((i0 + 1) * (62 - i0)) >> 1; }
        else if (st0 > c0) { i0--; stn0 = st0; st0 = (i0 * (63 - i0)) >> 1; }
        feat[0] = i0;
        feat[1] = c0 - st0 + i0 + 1;
        // c1 = c0 + 1: same first element unless c1 starts the next block.
        const int c1 = c0 + 1;
        int i1 = i0, st1 = st0;
        if (stn0 <= c1) { i1 = i0 + 1; st1 = stn0; }
        feat[2] = i1;
        feat[3] = c1 - st1 + i1 + 1;
    }
    __syncthreads();

    if (g >= G_PER_ROW) return;

    if (full) {
        // Branch-free: 16 independent LDS-gather + nt-store iterations.
        f32x4* outp = reinterpret_cast<f32x4*>(out + (size_t)row0 * NCR) + g;
        #pragma unroll
        for (int r = 0; r < ROWS_PER_BLOCK; ++r) {
            const float* rowp = lds + r * FDIM;   // same row across lanes
            f32x4 v;
            v.x = rowp[feat[0]];
            v.y = rowp[feat[1]];
            v.z = rowp[feat[2]];
            v.w = rowp[feat[3]];
            __builtin_nontemporal_store(v, outp);  // stream past L2
            outp += NCR / 4;
        }
    } else {
        #pragma unroll
        for (int r = 0; r < ROWS_PER_BLOCK; ++r) {
            int row = row0 + r;
            if (row >= nrows) break;
            const float* rowp = lds + r * FDIM;
            f32x4 v;
            v.x = rowp[feat[0]];
            v.y = rowp[feat[1]];
            v.z = rowp[feat[2]];
            v.w = rowp[feat[3]];
            __builtin_nontemporal_store(
                v, reinterpret_cast<f32x4*>(out + (size_t)row * NCR) + g);
        }
    }
}

extern "C" void kernel_launch(void* const* d_in, const int* in_sizes, int n_in,
                              void* d_out, int out_size, void* d_ws, size_t ws_size,
                              hipStream_t stream) {
    const float* x  = (const float*)d_in[0];
    float* out      = (float*)d_out;
    int nrows = in_sizes[0] / FDIM;                       // 32*4096 = 131072
    int grid  = (nrows + ROWS_PER_BLOCK - 1) / ROWS_PER_BLOCK;  // 8192
    hipLaunchKernelGGL(comb_gather_kernel, dim3(grid), dim3(BLOCK), 0, stream,
                       x, out, nrows);
}